// Round 1
// baseline (14768.907 us; speedup 1.0000x reference)
//
#include <hip/hip_runtime.h>

#define HSZ 128
#define NEGRID 100

// ---------- float <-> order-preserving uint (for atomic float max) ----------
__device__ __forceinline__ unsigned encf(float f) {
  unsigned i = __float_as_uint(f);
  return (i & 0x80000000u) ? ~i : (i | 0x80000000u);
}
__device__ __forceinline__ float decf(unsigned u) {
  return (u & 0x80000000u) ? __uint_as_float(u & 0x7fffffffu) : __uint_as_float(~u);
}

// ---------- h = x@node_w + node_b ; e = edge_attr@edgep_w + edgep_b ----------
__global__ void k_embed(const float* __restrict__ x, const float* __restrict__ ea,
                        const float* __restrict__ nw, const float* __restrict__ nb,
                        const float* __restrict__ ew, const float* __restrict__ eb,
                        float* __restrict__ h, float* __restrict__ e,
                        float* __restrict__ smean, int N, int E) {
  int row = blockIdx.x, c = threadIdx.x;
  if (row == 0 && c < 16) smean[c] = 0.f;
  if (row < N) {
    float acc = nb[c];
#pragma unroll
    for (int k = 0; k < 4; ++k) acc += x[row * 4 + k] * nw[k * 128 + c];
    h[row * 128 + c] = acc;
  } else {
    int ei = row - N;
    float acc = eb[c];
#pragma unroll
    for (int k = 0; k < 5; ++k) acc += ea[ei * 5 + k] * ew[k * 128 + c];
    e[ei * 128 + c] = acc;
  }
}

// ---------- per layer: xl = h@W (nodes), s_src/s_dst per node; s_edge per edge ----------
__global__ void k_gat_lin(const float* __restrict__ h, const float* __restrict__ e,
                          const float* __restrict__ W, const float* __restrict__ We,
                          const float* __restrict__ asrc, const float* __restrict__ adst,
                          const float* __restrict__ aedge,
                          float* __restrict__ xl, float* __restrict__ ssrc,
                          float* __restrict__ sdst, float* __restrict__ sedge,
                          float* __restrict__ smean4, unsigned* __restrict__ menc,
                          float* __restrict__ den, float* __restrict__ outacc,
                          int N, int E) {
  __shared__ float row_lds[128];
  __shared__ float red[128];
  __shared__ float red2[128];
  int row = blockIdx.x, c = threadIdx.x;
  const float* M;
  if (row < N) { row_lds[c] = h[row * 128 + c]; M = W; }
  else         { row_lds[c] = e[(row - N) * 128 + c]; M = We; }
  __syncthreads();
  float acc = 0.f;
  for (int k = 0; k < 128; ++k) acc += row_lds[k] * M[k * 128 + c];
  if (row < N) {
    xl[row * 128 + c] = acc;
    outacc[row * 128 + c] = 0.f;
    if (c < 4) { menc[row * 4 + c] = 0u; den[row * 4 + c] = 0.f; }
    red[c]  = acc * asrc[c];
    red2[c] = acc * adst[c];
    __syncthreads();
    if (c < 8) {
      int hh = c & 3;
      const float* b = (c < 4) ? red : red2;
      float s = 0.f;
      for (int t = 0; t < 32; ++t) s += b[hh * 32 + t];
      if (c < 4) ssrc[row * 4 + hh] = s; else sdst[row * 4 + hh] = s;
    }
  } else {
    int ei = row - N;
    red[c] = acc * aedge[c];
    __syncthreads();
    if (c < 4) {
      float s = 0.f;
      for (int t = 0; t < 32; ++t) s += red[c * 32 + t];
      sedge[ei * 4 + c] = s;
      atomicAdd(&smean4[c], s);
    }
  }
}

// ---------- alpha (leaky-relu) + atomic segment max over dst ----------
__global__ void k_alpha(const float* __restrict__ ssrc, const float* __restrict__ sdst,
                        const float* __restrict__ sedge, const float* __restrict__ smean4,
                        const int* __restrict__ srcI, const int* __restrict__ dstI,
                        float* __restrict__ alpha, unsigned* __restrict__ menc,
                        int N, int E, float invE) {
  int gid = blockIdx.x * 256 + threadIdx.x;
  if (gid >= (E + N) * 4) return;
  int item = gid >> 2, hh = gid & 3;
  float a; int dnode;
  if (item < E) {
    a = ssrc[srcI[item] * 4 + hh] + sdst[dstI[item] * 4 + hh] + sedge[item * 4 + hh];
    dnode = dstI[item];
  } else {
    int n = item - E;
    a = ssrc[n * 4 + hh] + sdst[n * 4 + hh] + smean4[hh] * invE;
    dnode = n;
  }
  a = (a > 0.f) ? a : 0.2f * a;
  alpha[gid] = a;
  atomicMax(&menc[dnode * 4 + hh], encf(a));
}

// ---------- exp + atomic den / weighted-feature scatter ----------
__global__ void k_scatter(const float* __restrict__ alpha, const unsigned* __restrict__ menc,
                          const float* __restrict__ xl, const int* __restrict__ srcI,
                          const int* __restrict__ dstI, float* __restrict__ den,
                          float* __restrict__ outacc, int N, int E) {
  int item = blockIdx.x, c = threadIdx.x, hh = c >> 5;
  int sn, dn;
  if (item < E) { sn = srcI[item]; dn = dstI[item]; } else { sn = dn = item - E; }
  float m = decf(menc[dn * 4 + hh]);
  float ex = expf(alpha[item * 4 + hh] - m);
  atomicAdd(&outacc[dn * 128 + c], xl[sn * 128 + c] * ex);
  if (c < 4) {
    float ex2 = expf(alpha[item * 4 + c] - decf(menc[dn * 4 + c]));
    atomicAdd(&den[dn * 4 + c], ex2);
  }
}

// ---------- hc = out/den + bias; h = LN(relu(hc)+h) ----------
__global__ void k_norm(const float* __restrict__ outacc, const float* __restrict__ den,
                       const float* __restrict__ bias, const float* __restrict__ lns,
                       const float* __restrict__ lnb, float* __restrict__ h, int N) {
  __shared__ float buf[128];
  int n = blockIdx.x, c = threadIdx.x, hh = c >> 5;
  float v = outacc[n * 128 + c] / den[n * 4 + hh] + bias[c];
  v = fmaxf(v, 0.f) + h[n * 128 + c];
  buf[c] = v;
  __syncthreads();
  for (int s = 64; s > 0; s >>= 1) { if (c < s) buf[c] += buf[c + s]; __syncthreads(); }
  float mean = buf[0] * (1.f / 128.f);
  __syncthreads();
  float dv = v - mean;
  buf[c] = dv * dv;
  __syncthreads();
  for (int s = 64; s > 0; s >>= 1) { if (c < s) buf[c] += buf[c + s]; __syncthreads(); }
  float var = buf[0] * (1.f / 128.f);
  h[n * 128 + c] = dv * (1.0f / sqrtf(var + 1e-5f)) * lns[c] + lnb[c];
}

// ---------- onsite / coupling MLPs (128 -> 64 -> 1) ----------
__global__ void k_mlp(const float* __restrict__ h, const float* __restrict__ e,
                      const float* __restrict__ w1n, const float* __restrict__ b1n,
                      const float* __restrict__ w2n, const float* __restrict__ b2n,
                      const float* __restrict__ w1e, const float* __restrict__ b1e,
                      const float* __restrict__ w2e, const float* __restrict__ b2e,
                      float* __restrict__ onsite, float* __restrict__ coup, int N, int E) {
  int row = blockIdx.x, t = threadIdx.x;
  const float *vec, *w1, *b1, *w2; float b2v;
  if (row < N) { vec = h + (size_t)row * 128; w1 = w1n; b1 = b1n; w2 = w2n; b2v = b2n[0]; }
  else         { vec = e + (size_t)(row - N) * 128; w1 = w1e; b1 = b1e; w2 = w2e; b2v = b2e[0]; }
  float acc = b1[t];
  for (int k = 0; k < 128; ++k) acc += vec[k] * w1[k * 64 + t];
  acc = fmaxf(acc, 0.f) * w2[t];
#pragma unroll
  for (int off = 32; off; off >>= 1) acc += __shfl_down(acc, off);
  if (t == 0) {
    float r = acc + b2v;
    if (row < N) onsite[row] = r; else coup[row - N] = r;
  }
}

// ---------- dna mask + per-graph local index (single wave) ----------
__global__ void k_dna(const float* __restrict__ x, const int* __restrict__ batch,
                      int* __restrict__ dna, int* __restrict__ loc, int N, int B) {
  __shared__ int perB[64];
  __shared__ int beforeB[64];
  int l = threadIdx.x;
  perB[l] = 0;
  __syncthreads();
  int chunk = (N + 63) >> 6;
  int s0 = l * chunk, s1 = min(N, s0 + chunk);
  int cnt = 0;
  for (int n = s0; n < s1; ++n) {
    int mi = (x[n * 4 + 0] != 0.f || x[n * 4 + 1] != 0.f ||
              x[n * 4 + 2] != 0.f || x[n * 4 + 3] != 0.f) ? 1 : 0;
    dna[n] = mi;
    cnt += mi;
    if (mi) atomicAdd(&perB[batch[n]], 1);
  }
  __syncthreads();
  int pre = cnt;
#pragma unroll
  for (int off = 1; off < 64; off <<= 1) {
    int o = __shfl_up(pre, off);
    if (l >= off) pre += o;
  }
  int excl = pre - cnt;
  if (l == 0) {
    int run = 0;
    for (int g = 0; g < B; ++g) { beforeB[g] = run; run += perB[g]; }
  }
  __syncthreads();
  int run = excl;
  for (int n = s0; n < s1; ++n) {
    loc[n] = run - beforeB[batch[n]];
    run += dna[n];
  }
}

// ---------- H init (0 off-diag, 1e-6 diag) ----------
__global__ void k_hinit(float* __restrict__ H, int total) {
  int idx = blockIdx.x * 256 + threadIdx.x;
  if (idx >= total) return;
  int ij = idx & (HSZ * HSZ - 1);
  H[idx] = ((ij >> 7) == (ij & 127)) ? 1e-6f : 0.f;
}

// ---------- H scatter-add: onsite diag + symmetric coupling ----------
__global__ void k_hadd(const int* __restrict__ dna, const int* __restrict__ loc,
                       const int* __restrict__ batch, const int* __restrict__ srcI,
                       const int* __restrict__ dstI, const float* __restrict__ onsite,
                       const float* __restrict__ coup, float* __restrict__ H, int N, int E) {
  int item = blockIdx.x * 256 + threadIdx.x;
  if (item >= N + E) return;
  if (item < N) {
    if (dna[item]) atomicAdd(&H[batch[item] * (HSZ * HSZ) + loc[item] * (HSZ + 1)], onsite[item]);
  } else {
    int ei = item - N;
    int s = srcI[ei], d = dstI[ei];
    if (dna[s] && dna[d]) {
      float cv = coup[ei];
      int b = batch[s];
      atomicAdd(&H[b * (HSZ * HSZ) + loc[s] * HSZ + loc[d]], cv);
      atomicAdd(&H[b * (HSZ * HSZ) + loc[d] * HSZ + loc[s]], cv);
    }
  }
}

// ---------- NEGF: Gr = inv((E*I - H) + i*diag(g)) via complex in-place ----------
// ---------- Gauss-Jordan w/ partial pivoting, register-resident 4x4 tiles ----------
__global__ __launch_bounds__(1024) void k_negf(
    const float* __restrict__ Hm, const float* __restrict__ GL, const float* __restrict__ GR,
    float* __restrict__ outT, float* __restrict__ outD) {
  int bid = blockIdx.x;
  int b = bid / NEGRID, eix = bid % NEGRID;
  float Ev = (float)(-3.0 + (6.0 / 99.0) * (double)eix);

  int tid = threadIdx.x;
  int tr = tid >> 5, tc = tid & 31;
  int r0 = tr << 2, c0 = tc << 2;

  __shared__ float gl_s[HSZ], gr_s[HSZ], g_s[HSZ];
  __shared__ float2 fcol[2][HSZ];
  __shared__ float fmag[2][HSZ];
  __shared__ float2 prow[160];  // padded index 5*tc+mc: <=2-way bank conflict
  __shared__ int colrow[HSZ];
  __shared__ float redbuf[32];

  if (tid < HSZ) {
    float a_ = GL[b * HSZ + tid], b_ = GR[b * HSZ + tid];
    gl_s[tid] = a_; gr_s[tid] = b_;
    g_s[tid] = 0.5f * (a_ + b_) + 1e-12f;
  }
  __syncthreads();

  float Wre[16], Wim[16];
  const float* Hb = Hm + (size_t)b * HSZ * HSZ;
#pragma unroll
  for (int mr = 0; mr < 4; ++mr) {
    int r = r0 + mr;
    const float4 hv = *(const float4*)(Hb + r * HSZ + c0);
    float hx0 = hv.x, hx1 = hv.y, hx2 = hv.z, hx3 = hv.w;
    float gr = g_s[r];
    Wre[mr * 4 + 0] = ((c0 + 0 == r) ? Ev : 0.f) - hx0;
    Wre[mr * 4 + 1] = ((c0 + 1 == r) ? Ev : 0.f) - hx1;
    Wre[mr * 4 + 2] = ((c0 + 2 == r) ? Ev : 0.f) - hx2;
    Wre[mr * 4 + 3] = ((c0 + 3 == r) ? Ev : 0.f) - hx3;
#pragma unroll
    for (int mc = 0; mc < 4; ++mc) Wim[mr * 4 + mc] = (c0 + mc == r) ? gr : 0.f;
  }

  int myrowcol[4] = {0, 0, 0, 0};
  unsigned pivmask = 0u;

  if (tc == 0) {  // stage column 0
#pragma unroll
    for (int mr = 0; mr < 4; ++mr) {
      float re = Wre[mr * 4], im = Wim[mr * 4];
      fcol[0][r0 + mr] = make_float2(re, im);
      fmag[0][r0 + mr] = re * re + im * im;
    }
  }
  __syncthreads();

  int lane = tid & 63;
  for (int k = 0; k < HSZ; ++k) {
    int par = k & 1;
    // --- redundant per-wave argmax over 128 pivot magnitudes (no barrier) ---
    float m1 = fmag[par][lane];
    float m2 = fmag[par][lane + 64];
    float mg = m1; int mi_ = lane;
    if (m2 > m1) { mg = m2; mi_ = lane + 64; }
#pragma unroll
    for (int off = 32; off; off >>= 1) {
      float om = __shfl_xor(mg, off);
      int oi = __shfl_xor(mi_, off);
      if (om > mg || (om == mg && oi < mi_)) { mg = om; mi_ = oi; }
    }
    int p = mi_;
    float2 piv = fcol[par][p];
    float idn = 1.0f / (piv.x * piv.x + piv.y * piv.y);
    float dre = piv.x * idn, dim = -piv.y * idn;

    // --- pivot-row owners: stage unscaled row, then scale row by d ---
    if ((p >> 2) == tr) {
      pivmask |= 1u << (p & 3);
      int mrp = p & 3;
#pragma unroll
      for (int mr = 0; mr < 4; ++mr) {
        if (mr != mrp) continue;
        myrowcol[mr] = k;
#pragma unroll
        for (int mc = 0; mc < 4; ++mc) {
          int j = c0 + mc;
          float re = Wre[mr * 4 + mc], im = Wim[mr * 4 + mc];
          prow[5 * tc + mc] = make_float2(re, im);
          float nre = re * dre - im * dim;
          float nim = re * dim + im * dre;
          if (j == k) { nre = dre; nim = dim; }
          Wre[mr * 4 + mc] = nre; Wim[mr * 4 + mc] = nim;
        }
      }
      if (tc == 0) colrow[k] = p;
    }
    __syncthreads();

    // --- eliminate all rows != p ---
    float2 pr0 = prow[5 * tc + 0], pr1 = prow[5 * tc + 1];
    float2 pr2 = prow[5 * tc + 2], pr3 = prow[5 * tc + 3];
    float2 pr[4] = {pr0, pr1, pr2, pr3};
#pragma unroll
    for (int mr = 0; mr < 4; ++mr) {
      int r = r0 + mr;
      if (r != p) {
        float2 f = fcol[par][r];
        float fdre = f.x * dre - f.y * dim;
        float fdim = f.x * dim + f.y * dre;
#pragma unroll
        for (int mc = 0; mc < 4; ++mc) {
          int j = c0 + mc;
          float re, im;
          if (j == k) { re = -fdre; im = -fdim; }
          else {
            re = Wre[mr * 4 + mc] - (fdre * pr[mc].x - fdim * pr[mc].y);
            im = Wim[mr * 4 + mc] - (fdre * pr[mc].y + fdim * pr[mc].x);
          }
          Wre[mr * 4 + mc] = re; Wim[mr * 4 + mc] = im;
        }
      }
    }
    // --- stage column k+1 into other parity buffer ---
    if (k < HSZ - 1) {
      int k2 = k + 1, par2 = par ^ 1;
      if ((k2 >> 2) == tc) {
        int mck = k2 & 3;
#pragma unroll
        for (int mr = 0; mr < 4; ++mr) {
          float re = 0.f, im = 0.f;
#pragma unroll
          for (int mc = 0; mc < 4; ++mc) {
            if (mc == mck) { re = Wre[mr * 4 + mc]; im = Wim[mr * 4 + mc]; }
          }
          bool pv = (pivmask >> mr) & 1u;
          fcol[par2][r0 + mr] = make_float2(re, im);
          fmag[par2][r0 + mr] = pv ? -1.f : (re * re + im * im);
        }
      }
    }
    __syncthreads();
  }

  // stored W[i][j] = Gr[ myrowcol[i] ][ colrow[j] ]  (permutation absorbed here)
  float Tacc = 0.f, Dacc = 0.f;
#pragma unroll
  for (int mr = 0; mr < 4; ++mr) {
    int rr = myrowcol[mr];
    float glv = gl_s[rr];
#pragma unroll
    for (int mc = 0; mc < 4; ++mc) {
      int cc = colrow[c0 + mc];
      float re = Wre[mr * 4 + mc], im = Wim[mr * 4 + mc];
      float g2 = re * re + im * im;
      Tacc += glv * gr_s[cc] * g2;
      if (rr == cc) Dacc += im;
    }
  }
#pragma unroll
  for (int off = 32; off; off >>= 1) {
    Tacc += __shfl_xor(Tacc, off);
    Dacc += __shfl_xor(Dacc, off);
  }
  int wv = tid >> 6;
  if (lane == 0) { redbuf[wv] = Tacc; redbuf[16 + wv] = Dacc; }
  __syncthreads();
  if (tid == 0) {
    float T = 0.f, D = 0.f;
    for (int w = 0; w < 16; ++w) { T += redbuf[w]; D += redbuf[16 + w]; }
    outT[bid] = log10f(fmaxf(T, 1e-16f));
    outD[bid] = log10f(fmaxf(-D * 0.31830988618379067f, 1e-16f));
  }
}

extern "C" void kernel_launch(void* const* d_in, const int* in_sizes, int n_in,
                              void* d_out, int out_size, void* d_ws, size_t ws_size,
                              hipStream_t stream) {
  const float* x     = (const float*)d_in[0];
  const int*   eidx  = (const int*)d_in[1];
  const float* eattr = (const float*)d_in[2];
  const int*   batch = (const int*)d_in[3];
  const float* GL    = (const float*)d_in[4];
  const float* GR    = (const float*)d_in[5];
  const float* node_w  = (const float*)d_in[6];
  const float* node_b  = (const float*)d_in[7];
  const float* edgep_w = (const float*)d_in[8];
  const float* edgep_b = (const float*)d_in[9];
  const float* gat_lin      = (const float*)d_in[10];
  const float* att_src      = (const float*)d_in[11];
  const float* att_dst      = (const float*)d_in[12];
  const float* gat_lin_edge = (const float*)d_in[13];
  const float* att_edge     = (const float*)d_in[14];
  const float* gat_bias     = (const float*)d_in[15];
  const float* ln_s = (const float*)d_in[16];
  const float* ln_b = (const float*)d_in[17];
  const float* on_w1 = (const float*)d_in[18];
  const float* on_b1 = (const float*)d_in[19];
  const float* on_w2 = (const float*)d_in[20];
  const float* on_b2 = (const float*)d_in[21];
  const float* cp_w1 = (const float*)d_in[22];
  const float* cp_b1 = (const float*)d_in[23];
  const float* cp_w2 = (const float*)d_in[24];
  const float* cp_b2 = (const float*)d_in[25];

  int N = in_sizes[0] / 4;
  int E = in_sizes[1] / 2;
  int B = in_sizes[4] / HSZ;
  const int* srcI = eidx;
  const int* dstI = eidx + E;

  float* ws = (float*)d_ws;
  size_t o = 0;
  float* h     = ws + o; o += (size_t)N * 128;
  float* ebuf  = ws + o; o += (size_t)E * 128;
  float* xl    = ws + o; o += (size_t)N * 128;
  float* ssrc  = ws + o; o += (size_t)N * 4;
  float* sdst  = ws + o; o += (size_t)N * 4;
  float* sedge = ws + o; o += (size_t)E * 4;
  float* smean = ws + o; o += 16;
  float* alpha = ws + o; o += (size_t)(E + N) * 4;
  unsigned* menc = (unsigned*)(ws + o); o += (size_t)N * 4;
  float* den    = ws + o; o += (size_t)N * 4;
  float* outacc = ws + o; o += (size_t)N * 128;
  float* onsite = ws + o; o += (size_t)((N + 3) & ~3);
  float* coup   = ws + o; o += (size_t)((E + 3) & ~3);
  int* dna = (int*)(ws + o); o += (size_t)((N + 3) & ~3);
  int* loc = (int*)(ws + o); o += (size_t)((N + 3) & ~3);

  float* out  = (float*)d_out;
  float* outT = out;
  float* outD = out + (size_t)B * NEGRID;
  float* outH = out + (size_t)2 * B * NEGRID;

  k_embed<<<N + E, 128, 0, stream>>>(x, eattr, node_w, node_b, edgep_w, edgep_b,
                                     h, ebuf, smean, N, E);
  for (int l = 0; l < 4; ++l) {
    k_gat_lin<<<N + E, 128, 0, stream>>>(
        h, ebuf, gat_lin + (size_t)l * 16384, gat_lin_edge + (size_t)l * 16384,
        att_src + l * 128, att_dst + l * 128, att_edge + l * 128,
        xl, ssrc, sdst, sedge, smean + l * 4, menc, den, outacc, N, E);
    int items = (E + N) * 4;
    k_alpha<<<(items + 255) / 256, 256, 0, stream>>>(
        ssrc, sdst, sedge, smean + l * 4, srcI, dstI, alpha, menc, N, E, 1.0f / (float)E);
    k_scatter<<<E + N, 128, 0, stream>>>(alpha, menc, xl, srcI, dstI, den, outacc, N, E);
    k_norm<<<N, 128, 0, stream>>>(outacc, den, gat_bias + l * 128,
                                  ln_s + l * 128, ln_b + l * 128, h, N);
  }
  k_mlp<<<N + E, 64, 0, stream>>>(h, ebuf, on_w1, on_b1, on_w2, on_b2,
                                  cp_w1, cp_b1, cp_w2, cp_b2, onsite, coup, N, E);
  k_dna<<<1, 64, 0, stream>>>(x, batch, dna, loc, N, B);
  int htot = B * HSZ * HSZ;
  k_hinit<<<(htot + 255) / 256, 256, 0, stream>>>(outH, htot);
  k_hadd<<<(N + E + 255) / 256, 256, 0, stream>>>(dna, loc, batch, srcI, dstI,
                                                  onsite, coup, outH, N, E);
  k_negf<<<B * NEGRID, 1024, 0, stream>>>(outH, GL, GR, outT, outD);
}